// Round 4
// baseline (783.464 us; speedup 1.0000x reference)
//
#include <hip/hip_runtime.h>

typedef unsigned short ushort_t;
typedef __attribute__((ext_vector_type(8))) short short8;   // 8 bf16 (4 VGPRs)
typedef __attribute__((ext_vector_type(4))) float f32x4;

#define C1 0.0625f                      // sqrt(2/512)
#define C2 0.029462782549439483f        // sqrt(2/2304)
#define C2SQ (2.0f/2304.0f)
#define C3 0.08838834764831845f         // sqrt(2/256)
#define C4 0.04419417382415922f         // sqrt(2/1024)

__device__ __forceinline__ float bf2f(ushort_t u) {
  union { unsigned int i; float f; } v; v.i = ((unsigned int)u) << 16; return v.f;
}
__device__ __forceinline__ ushort_t f2bf(float f) {
  union { float f; unsigned int i; } v; v.f = f;
  unsigned int r = v.i + 0x7fffu + ((v.i >> 16) & 1u);   // RNE
  return (ushort_t)(r >> 16);
}
__device__ __forceinline__ void async16(const void* g, void* l) {
  __builtin_amdgcn_global_load_lds(
      (const __attribute__((address_space(1))) unsigned int*)g,
      (__attribute__((address_space(3))) unsigned int*)l, 16, 0, 0);
}
__device__ __forceinline__ float lrelu(float v) { return v > 0.f ? v : 0.2f * v; }

// ---------------- prep: style vector s[b][i] (f32 in, f32 out) ----------------
__global__ void k_style(const float* __restrict__ latent, const float* __restrict__ stdW,
                        const float* __restrict__ stdb, float* __restrict__ s) {
  __shared__ float red[256];
  int b = blockIdx.x, ic = blockIdx.y;
  int il = threadIdx.x & 31, lp = threadIdx.x >> 5;
  int i = (ic << 5) + il;
  float acc = 0.f;
  int l0 = lp << 6;
  for (int l = l0; l < l0 + 64; ++l)
    acc += latent[(b << 9) + l] * stdW[(l << 8) + i];
  red[threadIdx.x] = acc;
  __syncthreads();
  if (lp == 0) {
    float v = 0.f;
#pragma unroll
    for (int p = 0; p < 8; ++p) v += red[(p << 5) + il];
    s[(b << 8) + i] = v * C1 + stdb[i];
  }
}

// ---------------- prep: w2[i][o] = c2^2 * sum_tap w^2 ----------------
__global__ void k_w2(const float* __restrict__ convw, float* __restrict__ w2) {
  int t = blockIdx.x * 256 + threadIdx.x;      // i*256+o
  float acc = 0.f;
#pragma unroll
  for (int tap = 0; tap < 9; ++tap) {
    float w = convw[tap * 65536 + t];
    acc += w * w;
  }
  w2[t] = acc * C2SQ;
}

// ---------------- prep: demod d[b][o] ----------------
__global__ void k_demod(const float* __restrict__ w2, const float* __restrict__ s,
                        float* __restrict__ dm) {
  __shared__ float red[256];
  int b = blockIdx.x, oc = blockIdx.y;
  int ol = threadIdx.x & 31, ip = threadIdx.x >> 5;
  int o = (oc << 5) + ol;
  float acc = 0.f;
  int i0 = ip << 5;
  for (int i = i0; i < i0 + 32; ++i) {
    float si = s[(b << 8) + i];
    acc += w2[(i << 8) + o] * si * si;
  }
  red[threadIdx.x] = acc;
  __syncthreads();
  if (ip == 0) {
    float v = 1e-8f;
#pragma unroll
    for (int p = 0; p < 8; ++p) v += red[(p << 5) + ol];
    dm[(b << 8) + o] = rsqrtf(v);
  }
}

// ---------------- prep: conv weights transposed+scaled wt[o][tap*256+i] (bf16) ----------------
__global__ void k_wt(const float* __restrict__ convw, ushort_t* __restrict__ wt) {
  int t = blockIdx.x * 256 + threadIdx.x;      // o*2304 + kk (write-coalesced)
  int o = t / 2304;
  int kk = t - o * 2304;
  int tap = kk >> 8, i = kk & 255;
  wt[t] = f2bf(convw[tap * 65536 + (i << 8) + o] * C2);
}

// ---------------- prep: W1t[n][k] = D1_W[k][n]*c3 ; W2t[o][k] = D2_W[k][o]*c4 (bf16) ----------------
__global__ void k_w1t(const float* __restrict__ d1w, ushort_t* __restrict__ w1t) {
  int t = blockIdx.x * 256 + threadIdx.x;      // n*256 + k
  int n = t >> 8, k = t & 255;
  w1t[t] = f2bf(d1w[(k << 10) + n] * C3);
}
__global__ void k_w2t(const float* __restrict__ d2w, ushort_t* __restrict__ w2t) {
  int t = blockIdx.x * 256 + threadIdx.x;      // o*1024 + k
  int o = t >> 10, k = t & 1023;
  w2t[t] = f2bf(d2w[(k << 8) + o] * C4);
}

// ---------------- prep: modulated + zero-padded input xs[8][130][130][256] (bf16) ----------------
__global__ void k_pad(const float* __restrict__ data, const float* __restrict__ s,
                      ushort_t* __restrict__ xs) {
  int tid = blockIdx.x * 256 + threadIdx.x;    // one thread = 8 channels
  int ci8 = tid & 31;
  int p = tid >> 5;                            // b*130*130 + yp*130 + xp
  int xp = p % 130;
  int q = p / 130;
  int yp = q % 130;
  int b = q / 130;
  short8 ov = {0, 0, 0, 0, 0, 0, 0, 0};
  if (yp >= 1 && yp <= 128 && xp >= 1 && xp <= 128) {
    const f32x4* src = (const f32x4*)(data + ((((b << 7) + (yp - 1)) << 7) + (xp - 1)) * 256 + (ci8 << 3));
    const f32x4* sp  = (const f32x4*)(s + (b << 8) + (ci8 << 3));
    f32x4 v0 = src[0], v1 = src[1];
    f32x4 s0 = sp[0],  s1 = sp[1];
#pragma unroll
    for (int j = 0; j < 4; ++j) ov[j]     = (short)f2bf(v0[j] * s0[j]);
#pragma unroll
    for (int j = 0; j < 4; ++j) ov[4 + j] = (short)f2bf(v1[j] * s1[j]);
  }
  *(short8*)(xs + ((size_t)tid << 3)) = ov;
}

// ================= conv3x3 implicit GEMM — 256x256 tile, 8-phase counted-vmcnt =================
// (unchanged from round 2 — verified)

#define SWZ_FLAT(flat, row) ((((flat) ^ (row)) & 7) << 3)   // swizzled k-chunk (in elements)

__device__ __forceinline__ void stage_a(const ushort_t* ximg, int y0, int h, int kt2,
                                        int t, ushort_t* dst) {
  int tap = kt2 >> 2;
  int ci0 = (kt2 & 3) << 6;
  int ky = (tap >= 6) ? 2 : (tap >= 3 ? 1 : 0);
  int kx = tap - ky * 3;
  const ushort_t* ga = ximg + ((y0 + h + ky) * 130 + kx) * 256 + ci0;
#pragma unroll
  for (int is = 0; is < 2; ++is) {
    int flat = t + (is << 9);
    int row = flat >> 3;
    int cil = SWZ_FLAT(flat, row);
    async16(ga + row * 256 + cil, dst + (flat << 3));
  }
}

__device__ __forceinline__ void stage_b(const ushort_t* wtp, int h, int kt2, int t, ushort_t* dst) {
  const ushort_t* gb = wtp + (kt2 << 6) + (size_t)(h << 7) * 2304;
#pragma unroll
  for (int is = 0; is < 2; ++is) {
    int flat = t + (is << 9);
    int row = flat >> 3;
    int cil = SWZ_FLAT(flat, row);
    async16(gb + (size_t)row * 2304 + cil, dst + (flat << 3));
  }
}

#define LOAD_A(BASE) {                                                        \
  _Pragma("unroll") for (int q = 0; q < 4; ++q) {                             \
    int lr = (wm << 6) + (q << 4) + (lane & 15);                              \
    int bo0 = (lr << 7) + ((lane >> 4) << 4);                                 \
    int sw = (lr & 7) << 4;                                                   \
    af[q][0] = *(const short8*)((BASE) + ((bo0      ) ^ sw));                 \
    af[q][1] = *(const short8*)((BASE) + ((bo0 + 64 ) ^ sw)); } }

#define LOAD_B(BASE, BF) {                                                    \
  _Pragma("unroll") for (int p = 0; p < 2; ++p) {                             \
    int lr = (wn << 5) + (p << 4) + (lane & 15);                              \
    int bo0 = (lr << 7) + ((lane >> 4) << 4);                                 \
    int sw = (lr & 7) << 4;                                                   \
    BF[p][0] = *(const short8*)((BASE) + ((bo0      ) ^ sw));                 \
    BF[p][1] = *(const short8*)((BASE) + ((bo0 + 64 ) ^ sw)); } }

#define MFMA_BLK(MH, NH, BF) {                                                \
  _Pragma("unroll") for (int q = 0; q < 4; ++q)                               \
    _Pragma("unroll") for (int p = 0; p < 2; ++p)                             \
      _Pragma("unroll") for (int ks = 0; ks < 2; ++ks)                        \
        acc[MH][NH][q][p] = __builtin_amdgcn_mfma_f32_16x16x32_bf16(          \
            af[q][ks], BF[p][ks], acc[MH][NH][q][p], 0, 0, 0); }

#define PH_BAR()  __builtin_amdgcn_s_barrier()
#define PH_LGKM() asm volatile("s_waitcnt lgkmcnt(0)" ::: "memory")
#define VM4()     asm volatile("s_waitcnt vmcnt(4)" ::: "memory")
#define PRIO1()   __builtin_amdgcn_s_setprio(1)
#define PRIO0()   __builtin_amdgcn_s_setprio(0)

__global__ __launch_bounds__(512, 2) void k_conv(
    const ushort_t* __restrict__ xs, const ushort_t* __restrict__ wt,
    const float* __restrict__ dmod, const float* __restrict__ bias,
    const float* __restrict__ ncoef, const float* __restrict__ noise,
    ushort_t* __restrict__ y) {
  __shared__ __align__(16) ushort_t lds[2][4][128 * 64];   // [buf][A0,A1,B0,B1][row*64+k]

  int bid0 = blockIdx.x;
  int bid = (bid0 & 7) * 64 + (bid0 >> 3);     // XCD swizzle (512 % 8 == 0, bijective)
  int m0 = bid << 8;
  int b = m0 >> 14;
  int y0 = (m0 & 16383) >> 7;                  // first of two image rows
  const ushort_t* ximg = xs + (size_t)b * (130 * 130 * 256);

  int t = threadIdx.x;
  int lane = t & 63;
  int wid = t >> 6;
  int wm = wid >> 2, wn = wid & 3;             // 2M x 4N waves

  const f32x4 fz = {0.f, 0.f, 0.f, 0.f};
  f32x4 acc[2][2][4][2];                       // [mh][nh][q][p]
#pragma unroll
  for (int a0 = 0; a0 < 2; ++a0)
#pragma unroll
    for (int a1 = 0; a1 < 2; ++a1)
#pragma unroll
      for (int a2 = 0; a2 < 4; ++a2)
#pragma unroll
        for (int a3 = 0; a3 < 2; ++a3) acc[a0][a1][a2][a3] = fz;

  short8 af[4][2], bf[2][2], bg[2][2];

  // prologue: stage tile 0 in FIFO order A0, B0, B1, A1  (8 loads outstanding)
  stage_a(ximg, y0, 0, 0, t, &lds[0][0][0]);
  stage_b(wt,        0, 0, t, &lds[0][2][0]);
  stage_b(wt,        1, 0, t, &lds[0][3][0]);
  stage_a(ximg, y0, 1, 0, t, &lds[0][1][0]);

#pragma unroll 1
  for (int kt = 0; kt < 35; ++kt) {
    int cb = kt & 1, nb = cb ^ 1;
    const char* a0b = (const char*)&lds[cb][0][0];
    const char* a1b = (const char*)&lds[cb][1][0];
    const char* b0b = (const char*)&lds[cb][2][0];
    const char* b1b = (const char*)&lds[cb][3][0];
    int kt2 = kt + 1;
    // P0 (mh0,nh0): needs A0,B0 of kt -> drained by vmcnt(4)
    VM4(); PH_BAR();
    LOAD_A(a0b); LOAD_B(b0b, bf);
    stage_a(ximg, y0, 0, kt2, t, &lds[nb][0][0]);
    PH_BAR(); PH_LGKM();
    PRIO1(); MFMA_BLK(0, 0, bf); PRIO0();
    // P1 (mh0,nh1): needs B1 of kt
    VM4(); PH_BAR();
    LOAD_B(b1b, bg);
    stage_b(wt, 0, kt2, t, &lds[nb][2][0]);
    PH_BAR(); PH_LGKM();
    PRIO1(); MFMA_BLK(0, 1, bg); PRIO0();
    // P2 (mh1,nh1): needs A1 of kt
    VM4(); PH_BAR();
    LOAD_A(a1b);
    stage_b(wt, 1, kt2, t, &lds[nb][3][0]);
    PH_BAR(); PH_LGKM();
    PRIO1(); MFMA_BLK(1, 1, bg); PRIO0();
    // P3 (mh1,nh0): registers only
    stage_a(ximg, y0, 1, kt2, t, &lds[nb][1][0]);
    PH_BAR();
    PRIO1(); MFMA_BLK(1, 0, bf); PRIO0();
  }
  // peeled last tile (kt=35, buffer 1, no staging): drain 8 -> 4 -> 2 -> 0
  {
    const char* a0b = (const char*)&lds[1][0][0];
    const char* a1b = (const char*)&lds[1][1][0];
    const char* b0b = (const char*)&lds[1][2][0];
    const char* b1b = (const char*)&lds[1][3][0];
    asm volatile("s_waitcnt vmcnt(4)" ::: "memory"); PH_BAR();
    LOAD_A(a0b); LOAD_B(b0b, bf);
    PH_BAR(); PH_LGKM();
    PRIO1(); MFMA_BLK(0, 0, bf); PRIO0();
    asm volatile("s_waitcnt vmcnt(2)" ::: "memory"); PH_BAR();
    LOAD_B(b1b, bg);
    PH_BAR(); PH_LGKM();
    PRIO1(); MFMA_BLK(0, 1, bg); PRIO0();
    asm volatile("s_waitcnt vmcnt(0)" ::: "memory"); PH_BAR();
    LOAD_A(a1b);
    PH_BAR(); PH_LGKM();
    PRIO1(); MFMA_BLK(1, 1, bg); PRIO0();
    PH_BAR();
    PRIO1(); MFMA_BLK(1, 0, bf); PRIO0();
  }

  // epilogue: demod + bias + noise + lrelu -> y (bf16)
#pragma unroll
  for (int mh = 0; mh < 2; ++mh)
#pragma unroll
    for (int nh = 0; nh < 2; ++nh)
#pragma unroll
      for (int p = 0; p < 2; ++p) {
        int o = (nh << 7) + (wn << 5) + (p << 4) + (lane & 15);
        float dv = dmod[(b << 8) + o];
        float bv = bias[o];
        float nc = ncoef[o];
#pragma unroll
        for (int q = 0; q < 4; ++q) {
          int mloc = (mh << 7) + (wm << 6) + (q << 4) + ((lane >> 4) << 2);
#pragma unroll
          for (int r = 0; r < 4; ++r) {
            int idx = (m0 + mloc + r) * 256 + o;
            float v = acc[mh][nh][q][p][r] * dv + bv + noise[idx] * nc;
            y[idx] = f2bf(lrelu(v));
          }
        }
      }
}

// ================= fused D1+D2 v2: resident swizzled y-tile + direct-global B frags =================
// BM=128, 512 thr (8 waves, 2M x 4N). y tile staged ONCE (64KB LDS, XOR-swizzled).
// B1/B2 fragments loaded global->reg (L2-hot, 2-deep prefetch) -> no B staging, no barriers in GEMMs.
// Only 2 barriers per nc chunk (around ly). ly stored swizzled -> conflict-free writes+reads.
__global__ __launch_bounds__(512, 2) void k_dense(
    const ushort_t* __restrict__ y, float* __restrict__ out,
    const ushort_t* __restrict__ w1t, const float* __restrict__ b1,
    const ushort_t* __restrict__ w2t, const float* __restrict__ b2) {
  __shared__ __align__(16) ushort_t ybuf[128 * 256];   // resident A tile, swizzled (64KB)
  __shared__ __align__(16) ushort_t ly[128 * 128];     // h chunk, swizzled (32KB)

  int bid0 = blockIdx.x;
  int bid = (bid0 & 7) * 128 + (bid0 >> 3);            // XCD swizzle, 1024%8==0 bijective
  int row0 = bid << 7;
  int t = threadIdx.x, lane = t & 63;
  int wid = t >> 6;
  int wm = wid >> 2, wn = wid & 3;                     // 2M x 4N
  int l15 = lane & 15, lhi = lane >> 4;

  // ---- stage y tile once (linear LDS dest, inverse-swizzled global source) ----
#pragma unroll
  for (int is = 0; is < 8; ++is) {
    int flat = t + (is << 9);
    int row = flat >> 5, c = flat & 31;
    int cs = c ^ (row & 7);
    async16(y + (size_t)(row0 + row) * 256 + (cs << 3), (char*)ybuf + ((size_t)flat << 4));
  }

  int asw = l15 & 7;                                   // (row & 7) for all fragment rows
  int arow[4];
#pragma unroll
  for (int q = 0; q < 4; ++q) arow[q] = (wm << 6) + (q << 4) + l15;

  const f32x4 fz = {0.f, 0.f, 0.f, 0.f};
  f32x4 oacc[4][4];
#pragma unroll
  for (int q = 0; q < 4; ++q)
#pragma unroll
    for (int p = 0; p < 4; ++p) oacc[q][p] = fz;

  asm volatile("s_waitcnt vmcnt(0)" ::: "memory");
  __syncthreads();

#pragma unroll 1
  for (int nc = 0; nc < 8; ++nc) {
    f32x4 hacc[4][2];
#pragma unroll
    for (int q = 0; q < 4; ++q)
#pragma unroll
      for (int p = 0; p < 2; ++p) hacc[q][p] = fz;

    // ---- GEMM1: h[128x128] = ybuf[128x256] @ W1t chunk, B frags direct from global ----
    const ushort_t* w1b = w1t + ((size_t)((nc << 7) + (wn << 5) + l15) << 8) + (lhi << 3);
    short8 b1f[4][2][2];                               // [kt][p][ks], static-indexed
#pragma unroll
    for (int kt = 0; kt < 2; ++kt)
#pragma unroll
      for (int p = 0; p < 2; ++p)
#pragma unroll
        for (int ks = 0; ks < 2; ++ks)
          b1f[kt][p][ks] = *(const short8*)(w1b + (p << 12) + (kt << 6) + (ks << 5));

#pragma unroll
    for (int kt = 0; kt < 4; ++kt) {
      if (kt < 2) {                                    // 2-deep prefetch
#pragma unroll
        for (int p = 0; p < 2; ++p)
#pragma unroll
          for (int ks = 0; ks < 2; ++ks)
            b1f[kt + 2][p][ks] = *(const short8*)(w1b + (p << 12) + ((kt + 2) << 6) + (ks << 5));
      }
      short8 af[4][2];
#pragma unroll
      for (int q = 0; q < 4; ++q)
#pragma unroll
        for (int ks = 0; ks < 2; ++ks)
          af[q][ks] = *(const short8*)((const char*)ybuf +
              (arow[q] << 9) + (kt << 7) + ((((ks << 2) + lhi) ^ asw) << 4));
#pragma unroll
      for (int q = 0; q < 4; ++q)
#pragma unroll
        for (int p = 0; p < 2; ++p)
#pragma unroll
          for (int ks = 0; ks < 2; ++ks)
            hacc[q][p] = __builtin_amdgcn_mfma_f32_16x16x32_bf16(
                af[q][ks], b1f[kt][p][ks], hacc[q][p], 0, 0, 0);
    }

    __syncthreads();                                   // prior nc's ly reads complete

    // prefetch first half of B2 frags (covers L2 latency under ly write)
    const ushort_t* w2b = w2t + ((size_t)((wn << 6) + l15) << 10) + (nc << 7) + (lhi << 3);
    short8 b2f[4][4];                                  // [ks][p]
#pragma unroll
    for (int ks = 0; ks < 2; ++ks)
#pragma unroll
      for (int p = 0; p < 4; ++p)
        b2f[ks][p] = *(const short8*)(w2b + (p << 14) + (ks << 5));

    // ---- ly = lrelu(hacc + b1), swizzled store ----
    float b1v0 = b1[(nc << 7) + (wn << 5) + l15];
    float b1v1 = b1[(nc << 7) + (wn << 5) + 16 + l15];
#pragma unroll
    for (int q = 0; q < 4; ++q)
#pragma unroll
      for (int p = 0; p < 2; ++p) {
        float bv = p ? b1v1 : b1v0;
        int nbase = (wn << 5) + (p << 4) + l15;
        int nch = nbase >> 3;
        int nlo = (nbase & 7) << 1;
#pragma unroll
        for (int r = 0; r < 4; ++r) {
          int m = (wm << 6) + (q << 4) + (lhi << 2) + r;
          int byt = (m << 8) + ((nch ^ (m & 7)) << 4) + nlo;
          *(ushort_t*)((char*)ly + byt) = f2bf(lrelu(hacc[q][p][r] + bv));
        }
      }
    __syncthreads();                                   // ly visible to all waves

    // ---- GEMM2: oacc += ly[128x128] @ W2t chunk ----
#pragma unroll
    for (int ks = 0; ks < 4; ++ks) {
      if (ks < 2) {                                    // 2-deep prefetch
#pragma unroll
        for (int p = 0; p < 4; ++p)
          b2f[ks + 2][p] = *(const short8*)(w2b + (p << 14) + ((ks + 2) << 5));
      }
      short8 af2[4];
#pragma unroll
      for (int q = 0; q < 4; ++q)
        af2[q] = *(const short8*)((const char*)ly +
            (arow[q] << 8) + ((((ks << 2) + lhi) ^ asw) << 4));
#pragma unroll
      for (int q = 0; q < 4; ++q)
#pragma unroll
        for (int p = 0; p < 4; ++p)
          oacc[q][p] = __builtin_amdgcn_mfma_f32_16x16x32_bf16(
              af2[q], b2f[ks][p], oacc[q][p], 0, 0, 0);
    }
  }

  // ---- epilogue: out = lrelu(oacc + b2) (f32) ----
#pragma unroll
  for (int p = 0; p < 4; ++p) {
    int o = (wn << 6) + (p << 4) + l15;
    float bv = b2[o];
#pragma unroll
    for (int q = 0; q < 4; ++q) {
#pragma unroll
      for (int r = 0; r < 4; ++r) {
        int m = (wm << 6) + (q << 4) + (lhi << 2) + r;
        out[(size_t)(row0 + m) * 256 + o] = lrelu(oacc[q][p][r] + bv);
      }
    }
  }
}

extern "C" void kernel_launch(void* const* d_in, const int* in_sizes, int n_in,
                              void* d_out, int out_size, void* d_ws, size_t ws_size,
                              hipStream_t stream) {
  const float* data   = (const float*)d_in[0];
  const float* latent = (const float*)d_in[1];
  const float* noise  = (const float*)d_in[2];
  const float* stdW   = (const float*)d_in[3];
  const float* stdb   = (const float*)d_in[4];
  const float* convw  = (const float*)d_in[5];
  const float* bias   = (const float*)d_in[6];
  const float* ncoef  = (const float*)d_in[7];
  const float* D1W    = (const float*)d_in[8];
  const float* D1b    = (const float*)d_in[9];
  const float* D2W    = (const float*)d_in[10];
  const float* D2b    = (const float*)d_in[11];
  float* out = (float*)d_out;

  char* ws = (char*)d_ws;
  float*    s    = (float*)ws;                       //      8 KB
  float*    dmod = (float*)(ws + 8192);              //      8 KB
  float*    w2   = (float*)(ws + 16384);             //    256 KB
  ushort_t* wt   = (ushort_t*)(ws + 278528);         //  1,179,648 B  wt[o][2304]
  ushort_t* w1t  = (ushort_t*)(ws + 1458176);        //    512 KB  w1t[n][256]
  ushort_t* w2t  = (ushort_t*)(ws + 1982464);        //    512 KB  w2t[o][1024]
  ushort_t* xs   = (ushort_t*)(ws + 2506752);        //  69,222,400 B  xs[8][130][130][256]
  ushort_t* yv   = (ushort_t*)(ws + 71729152);       //  67,108,864 B  y[8*128*128][256]
                                                     //  total ~139 MB

  k_style<<<dim3(8, 8), 256, 0, stream>>>(latent, stdW, stdb, s);
  k_w2<<<256, 256, 0, stream>>>(convw, w2);
  k_demod<<<dim3(8, 8), 256, 0, stream>>>(w2, s, dmod);
  k_wt<<<2304, 256, 0, stream>>>(convw, wt);
  k_w1t<<<1024, 256, 0, stream>>>(D1W, w1t);
  k_w2t<<<1024, 256, 0, stream>>>(D2W, w2t);
  k_pad<<<16900, 256, 0, stream>>>(data, s, xs);     // 16900*256 threads = 8*130*130*32 exactly
  k_conv<<<512, 512, 0, stream>>>(xs, wt, dmod, bias, ncoef, noise, yv);
  k_dense<<<1024, 512, 0, stream>>>(yv, out, w1t, D1b, w2t, D2b);
}